// Round 9
// baseline (237.915 us; speedup 1.0000x reference)
//
#include <hip/hip_runtime.h>

#define B_    4
#define C_    256
#define O_    128
#define N_    4096
#define THW   256     // thph row width (theta | phi)
#define TILES 64      // N/64 key tiles (attn uses TK=64)

typedef __attribute__((ext_vector_type(8))) _Float16 f16x8;
typedef __attribute__((ext_vector_type(4))) float    f32x4;

struct __align__(8) us4 { unsigned short x, y, z, w; };

__device__ __forceinline__ float bf2f(unsigned short u) {
    unsigned v = ((unsigned)u) << 16;
    union { unsigned u; float f; } c; c.u = v; return c.f;
}
__device__ __forceinline__ unsigned short f2bf(float f) {
    union { float f; unsigned u; } c; c.f = f;
    unsigned r = c.u + 0x7fffu + ((c.u >> 16) & 1u);
    return (unsigned short)(r >> 16);
}
__device__ __forceinline__ unsigned short f2h(float f) {
    _Float16 h = (_Float16)f;
    union { _Float16 h; unsigned short s; } c; c.h = h; return c.s;
}
__device__ __forceinline__ float h2f(unsigned short s) {
    union { unsigned short s; _Float16 h; } c; c.s = s; return (float)c.h;
}

__device__ __forceinline__ void load4f(const void* base, size_t idx, int isf32, float o[4]) {
    if (isf32) {
        float4 v = *(const float4*)((const float*)base + idx);
        o[0] = v.x; o[1] = v.y; o[2] = v.z; o[3] = v.w;
    } else {
        us4 v = *(const us4*)((const unsigned short*)base + idx);
        o[0] = bf2f(v.x); o[1] = bf2f(v.y); o[2] = bf2f(v.z); o[3] = bf2f(v.w);
    }
}
__device__ __forceinline__ float load1f(const void* base, size_t idx, int isf32) {
    return isf32 ? ((const float*)base)[idx] : bf2f(((const unsigned short*)base)[idx]);
}

// ---------------------------------------------------------------------------
// Kernel 0: input dtype detector (fp32 confirmed live; kept for robustness).
// ---------------------------------------------------------------------------
__global__ __launch_bounds__(256) void detect_kernel(
    const unsigned short* __restrict__ xu, int* __restrict__ flag)
{
    __shared__ int cnt;
    if (threadIdx.x == 0) cnt = 0;
    __syncthreads();
    int local = 0;
    for (int i = threadIdx.x; i < 4096; i += 256) {
        unsigned short u = xu[2 * i];
        int e = (u >> 7) & 0xFF;
        if (e == 0xFF || e >= 0x90 || (e > 0 && e <= 0x60)) local++;
    }
    atomicAdd(&cnt, local);
    __syncthreads();
    if (threadIdx.x == 0) *flag = (cnt > 1024) ? 1 : 0;
}

// ---------------------------------------------------------------------------
// Kernel 1 (rewritten): all three conv1x1 in ONE block per 64-n tile.
// grid (N/64, B), 512 threads (8 waves = 2 wv_n x 4 wv_jg).
// - A-operand (x columns) loaded straight into registers upfront: lane l16
//   spans 16 consecutive n -> coalesced 64B segments; no LDS transpose.
// - Weights (384 j x 256 c) double-buffered in LDS by 32-c chunks with
//   2-deep register prefetch: ONE barrier per chunk.
// - Outputs: j<256 -> thph[b][n][j]; j>=256 -> g, transposed via LDS (reusing
//   Bs space) into gT[b][j][N] for attention's conflict-free staging.
// ---------------------------------------------------------------------------
__global__ __launch_bounds__(512, 2) void qkv_kernel(
    const void* __restrict__ x,    // [B][C][N] fp32 or bf16
    const void* __restrict__ wt, const void* __restrict__ wp,
    const void* __restrict__ wg,
    const void* __restrict__ bt, const void* __restrict__ bp,
    const void* __restrict__ bg,
    const int*  __restrict__ flag,
    unsigned short* __restrict__ thph,  // fp16 [B][N][256]
    unsigned short* __restrict__ gT)    // fp16 [B][128][N]
{
    const int isf32 = *flag;
    const int b  = blockIdx.y;
    const int n0 = blockIdx.x * 64;
    const int tid  = threadIdx.x;
    const int wv   = tid >> 6, lane = tid & 63;
    const int quad = lane >> 4, l16 = lane & 15;
    const int wv_n = wv & 1;        // n-half (2 x 16-row subtiles)
    const int wv_jg = wv >> 1;      // j-group (96 j each)

    // LDS: weight double-buffer; T (gT transpose) reuses the same space.
    __shared__ alignas(16) unsigned short smem[2 * 384 * 40];  // 61440 B
    unsigned short (*Bs)[384][40] = (unsigned short(*)[384][40])smem;
    unsigned short (*T)[68] = (unsigned short(*)[68])smem;     // [128][68]

    // ---- upfront A fragments: areg[a][chunk] = A[n=16-row tile][k=32 c] ----
    f16x8 areg[2][8];
    #pragma unroll
    for (int a = 0; a < 2; a++) {
        int n = n0 + (wv_n * 2 + a) * 16 + l16;
        #pragma unroll
        for (int s8 = 0; s8 < 8; s8++) {
            f16x8 fr;
            #pragma unroll
            for (int e = 0; e < 8; e++) {
                int c = s8 * 32 + quad * 8 + e;
                fr[e] = (_Float16)load1f(x, (size_t)(b * C_ + c) * N_ + n, isf32);
            }
            areg[a][s8] = fr;
        }
    }

    // ---- weight chunk load/stage helpers ----
    us4 wreg[2][6];
    auto loadW = [&](int s8, int slot) {
        #pragma unroll
        for (int it = 0; it < 6; it++) {
            int idx = it * 512 + tid;           // [0,3072) us4 units
            int j = idx >> 3, cg = idx & 7;     // j in [0,384), c = s8*32+cg*4
            const void* wsel = j < 128 ? wt : (j < 256 ? wp : wg);
            float v[4];
            load4f(wsel, (size_t)(j & 127) * C_ + s8 * 32 + cg * 4, isf32, v);
            us4 h;
            h.x = f2h(v[0]); h.y = f2h(v[1]); h.z = f2h(v[2]); h.w = f2h(v[3]);
            wreg[slot][it] = h;
        }
    };
    auto stageW = [&](int buf, int slot) {
        #pragma unroll
        for (int it = 0; it < 6; it++) {
            int idx = it * 512 + tid;
            int j = idx >> 3, cg = idx & 7;
            *(us4*)&Bs[buf][0][j * 40 + cg * 4] = wreg[slot][it];
        }
    };

    loadW(0, 0);
    loadW(1, 1);
    stageW(0, 0);          // waits on chunk-0 regs only

    f32x4 acc[2][6];
    #pragma unroll
    for (int a = 0; a < 2; a++)
        for (int jt = 0; jt < 6; jt++) acc[a][jt] = (f32x4)0.f;

    for (int i = 0; i < 8; i++) {
        __syncthreads();   // chunk i staged & prior-buffer reads complete
        int buf = i & 1;
        f16x8 bfrag[6];
        #pragma unroll
        for (int jt = 0; jt < 6; jt++)
            bfrag[jt] = *(const f16x8*)&Bs[buf][0][(wv_jg * 96 + jt * 16 + l16) * 40 + quad * 8];
        #pragma unroll
        for (int a = 0; a < 2; a++)
            #pragma unroll
            for (int jt = 0; jt < 6; jt++)
                acc[a][jt] = __builtin_amdgcn_mfma_f32_16x16x32_f16(
                    areg[a][i], bfrag[jt], acc[a][jt], 0, 0, 0);
        if (i + 1 < 8) {
            stageW((i + 1) & 1, (i + 1) & 1);      // write other buffer
            if (i + 2 < 8) loadW(i + 2, i & 1);    // refill consumed slot
        }
    }

    // ---- epilogue: D col=j(l16), row=n(quad*4+r) ----
    // theta/phi (j<256) straight to thph
    #pragma unroll
    for (int a = 0; a < 2; a++) {
        #pragma unroll
        for (int jt = 0; jt < 6; jt++) {
            int j = wv_jg * 96 + jt * 16 + l16;
            if (j < 256) {
                const void* bsel = j < 128 ? bt : bp;
                float bias = load1f(bsel, j & 127, isf32);
                #pragma unroll
                for (int r = 0; r < 4; r++) {
                    int n = n0 + (wv_n * 2 + a) * 16 + quad * 4 + r;
                    thph[(size_t)(b * N_ + n) * THW + j] = f2h(acc[a][jt][r] + bias);
                }
            }
        }
    }
    // g (j>=256): transpose via LDS (reuses Bs space) -> gT coalesced
    __syncthreads();   // all Bs reads done before overwrite
    #pragma unroll
    for (int a = 0; a < 2; a++) {
        #pragma unroll
        for (int jt = 0; jt < 6; jt++) {
            int j = wv_jg * 96 + jt * 16 + l16;
            if (j >= 256) {
                float bias = load1f(bg, j - 256, isf32);
                #pragma unroll
                for (int r = 0; r < 4; r++) {
                    int nl = (wv_n * 2 + a) * 16 + quad * 4 + r;
                    T[j - 256][nl] = f2h(acc[a][jt][r] + bias);
                }
            }
        }
    }
    __syncthreads();
    #pragma unroll
    for (int it = 0; it < 4; it++) {
        int idx = it * 512 + tid;   // [0,2048) us4
        int j = idx >> 4, ng = idx & 15;
        *(us4*)(gT + ((size_t)(b * O_ + j)) * N_ + n0 + ng * 4) = *(const us4*)&T[j][ng * 4];
    }
}

// ---------------------------------------------------------------------------
// Kernel 2: flash-attention partial (unchanged structure; S up to 6 ->
// 768 blocks = 3 blocks/CU, LDS 3x54272 = 162816 <= 163840).
// ---------------------------------------------------------------------------
__global__ __launch_bounds__(512, 4) void attn_partial(
    const unsigned short* __restrict__ thph,  // fp16 [B][N][256]
    const unsigned short* __restrict__ gT,    // fp16 [B][128][N]
    unsigned short* __restrict__ partO,       // fp16 [S][B][N][128]
    float* __restrict__ pm,                   // [S][B][N]
    float* __restrict__ pl,                   // [S][B][N]
    int S)
{
    const int b    = blockIdx.z;
    const int s_id = blockIdx.y;
    const int n0   = blockIdx.x * 128;
    const int tid  = threadIdx.x;
    const int wv   = tid >> 6, lane = tid & 63;
    const int quad = lane >> 4, l16 = lane & 15;

    const int t0 = (TILES * s_id) / S;
    const int t1 = (TILES * (s_id + 1)) / S;

    __shared__ alignas(16) unsigned short Ks[64][136];
    __shared__ alignas(16) unsigned short Gs[128][72];
    __shared__ alignas(16) unsigned short Ps[8][16][72];

    f16x8 qf[4];
    {
        int qrow = n0 + wv * 16 + l16;
        const unsigned short* qp = thph + (size_t)(b * N_ + qrow) * THW;
        for (int s = 0; s < 4; s++)
            qf[s] = *(const f16x8*)(qp + s * 32 + quad * 8);
    }

    f32x4 oacc[8];
    for (int i = 0; i < 8; i++) oacc[i] = (f32x4)0.f;
    float mstate = -INFINITY, lstate = 0.f;

    us4 kreg[4], greg[4];
    auto prefetch = [&](int mt) {
        int m0 = mt * 64;
        #pragma unroll
        for (int it = 0; it < 4; it++) {
            int l = it * 512 + tid;
            int mm = l >> 5, og = l & 31;
            kreg[it] = *(const us4*)(thph + (size_t)(b * N_ + m0 + mm) * THW + O_ + og * 4);
        }
        #pragma unroll
        for (int it = 0; it < 4; it++) {
            int l = it * 512 + tid;
            int o = l >> 4, ng = l & 15;
            greg[it] = *(const us4*)(gT + ((size_t)(b * O_ + o)) * N_ + m0 + ng * 4);
        }
    };
    prefetch(t0);

    for (int mt = t0; mt < t1; mt++) {
        __syncthreads();
        #pragma unroll
        for (int it = 0; it < 4; it++) {
            int l = it * 512 + tid;
            int mm = l >> 5, og = l & 31;
            *(us4*)&Ks[mm][og * 4] = kreg[it];
        }
        #pragma unroll
        for (int it = 0; it < 4; it++) {
            int l = it * 512 + tid;
            int o = l >> 4, ng = l & 15;
            *(us4*)&Gs[o][ng * 4] = greg[it];
        }
        __syncthreads();
        if (mt + 1 < t1) prefetch(mt + 1);

        f32x4 sacc[4];
        for (int kt = 0; kt < 4; kt++) sacc[kt] = (f32x4)0.f;
        for (int s = 0; s < 4; s++) {
            for (int kt = 0; kt < 4; kt++) {
                f16x8 kb = *(const f16x8*)&Ks[kt * 16 + l16][s * 32 + quad * 8];
                sacc[kt] = __builtin_amdgcn_mfma_f32_16x16x32_f16(kb, qf[s], sacc[kt], 0, 0, 0);
            }
        }

        float rm = fmaxf(fmaxf(fmaxf(sacc[0][0], sacc[0][1]), fmaxf(sacc[0][2], sacc[0][3])),
                         fmaxf(fmaxf(sacc[1][0], sacc[1][1]), fmaxf(sacc[1][2], sacc[1][3])));
        rm = fmaxf(rm, fmaxf(fmaxf(fmaxf(sacc[2][0], sacc[2][1]), fmaxf(sacc[2][2], sacc[2][3])),
                             fmaxf(fmaxf(sacc[3][0], sacc[3][1]), fmaxf(sacc[3][2], sacc[3][3]))));
        rm = fmaxf(rm, __shfl_xor(rm, 16));
        rm = fmaxf(rm, __shfl_xor(rm, 32));

        float mnew  = fmaxf(mstate, rm);
        float alpha = __expf(mstate - mnew);
        mstate = mnew;

        float rs = 0.f;
        #pragma unroll
        for (int kt = 0; kt < 4; kt++) {
            float p0 = __expf(sacc[kt][0] - mnew);
            float p1 = __expf(sacc[kt][1] - mnew);
            float p2 = __expf(sacc[kt][2] - mnew);
            float p3 = __expf(sacc[kt][3] - mnew);
            rs += (p0 + p1) + (p2 + p3);
            us4 pk;
            pk.x = f2h(p0); pk.y = f2h(p1); pk.z = f2h(p2); pk.w = f2h(p3);
            *(us4*)&Ps[wv][l16][kt * 16 + quad * 4] = pk;
        }
        rs += __shfl_xor(rs, 16);
        rs += __shfl_xor(rs, 32);
        lstate = lstate * alpha + rs;

        float av[4];
        #pragma unroll
        for (int r = 0; r < 4; r++) av[r] = __shfl(alpha, quad * 4 + r);
        #pragma unroll
        for (int jt = 0; jt < 8; jt++)
            #pragma unroll
            for (int r = 0; r < 4; r++) oacc[jt][r] *= av[r];

        for (int s = 0; s < 2; s++) {
            f16x8 pa = *(const f16x8*)&Ps[wv][l16][s * 32 + quad * 8];
            for (int jt = 0; jt < 8; jt++) {
                f16x8 gb = *(const f16x8*)&Gs[jt * 16 + l16][s * 32 + quad * 8];
                oacc[jt] = __builtin_amdgcn_mfma_f32_16x16x32_f16(pa, gb, oacc[jt], 0, 0, 0);
            }
        }
    }

    for (int r = 0; r < 4; r++) {
        int n = n0 + wv * 16 + quad * 4 + r;
        size_t rowb = ((size_t)(s_id * B_ + b) * N_ + n) * O_;
        for (int jt = 0; jt < 8; jt++)
            partO[rowb + jt * 16 + l16] = f2h(oacc[jt][r]);
    }
    if (quad == 0) {
        int n = n0 + wv * 16 + l16;
        pm[(size_t)(s_id * B_ + b) * N_ + n] = mstate;
        pl[(size_t)(s_id * B_ + b) * N_ + n] = lstate;
    }
}

// ---------------------------------------------------------------------------
// Kernel 2b: merge split-K partials -> y[b][n][o] (normalized fp16).
// ---------------------------------------------------------------------------
__global__ __launch_bounds__(256) void merge_kernel(
    const unsigned short* __restrict__ partO,
    const float* __restrict__ pm, const float* __restrict__ pl,
    unsigned short* __restrict__ y,
    int S)
{
    int idx = blockIdx.x * 256 + threadIdx.x;
    int bn  = idx >> 5;
    int og  = idx & 31;
    const int BN = B_ * N_;

    float M = -INFINITY;
    for (int s = 0; s < S; s++) M = fmaxf(M, pm[(size_t)s * BN + bn]);
    float w[8];
    float L = 0.f;
    for (int s = 0; s < S; s++) {
        w[s] = __expf(pm[(size_t)s * BN + bn] - M);
        L += w[s] * pl[(size_t)s * BN + bn];
    }
    float inv = 1.0f / L;

    float a0 = 0.f, a1 = 0.f, a2 = 0.f, a3 = 0.f;
    for (int s = 0; s < S; s++) {
        us4 v = *(const us4*)(partO + ((size_t)s * BN + bn) * O_ + og * 4);
        a0 += h2f(v.x) * w[s];
        a1 += h2f(v.y) * w[s];
        a2 += h2f(v.z) * w[s];
        a3 += h2f(v.w) * w[s];
    }
    us4 r;
    r.x = f2h(a0 * inv); r.y = f2h(a1 * inv);
    r.z = f2h(a2 * inv); r.w = f2h(a3 * inv);
    *(us4*)(y + (size_t)bn * O_ + og * 4) = r;
}

// ---------------------------------------------------------------------------
// Kernel 3: z[b][c][n] = sum_o wW[c][o] y[b][n][o] + bW[c] + x[b][c][n]
// ---------------------------------------------------------------------------
__global__ __launch_bounds__(256) void out_kernel(
    const unsigned short* __restrict__ y,
    const void* __restrict__ wW,
    const void* __restrict__ bW,
    const void* __restrict__ x,
    const int*  __restrict__ flag,
    void* __restrict__ z)
{
    const int isf32 = *flag;
    const int b  = blockIdx.z;
    const int c0 = blockIdx.y * 64;
    const int n0 = blockIdx.x * 128;
    const int tid  = threadIdx.x;
    const int wv   = tid >> 6, lane = tid & 63;
    const int quad = lane >> 4, l16 = lane & 15;

    __shared__ alignas(16) unsigned short Ys[128][136];
    __shared__ alignas(16) unsigned short Ws[64][136];

    for (int it = 0; it < 16; it++) {
        int l = it * 256 + tid;
        int nn = l >> 5;
        int og = l & 31;
        us4 v = *(const us4*)(y + (size_t)(b * N_ + n0 + nn) * O_ + og * 4);
        *(us4*)&Ys[nn][og * 4] = v;
    }
    for (int it = 0; it < 8; it++) {
        int l = it * 256 + tid;
        int cc = l >> 5;
        int og = l & 31;
        float v[4];
        load4f(wW, (size_t)(c0 + cc) * O_ + og * 4, isf32, v);
        Ws[cc][og * 4 + 0] = f2h(v[0]);
        Ws[cc][og * 4 + 1] = f2h(v[1]);
        Ws[cc][og * 4 + 2] = f2h(v[2]);
        Ws[cc][og * 4 + 3] = f2h(v[3]);
    }
    __syncthreads();

    f32x4 acc[8];
    for (int i = 0; i < 8; i++) acc[i] = (f32x4)0.f;
    for (int s = 0; s < 4; s++) {
        f16x8 a = *(const f16x8*)&Ws[wv * 16 + l16][s * 32 + quad * 8];
        for (int nt = 0; nt < 8; nt++) {
            f16x8 bb = *(const f16x8*)&Ys[nt * 16 + l16][s * 32 + quad * 8];
            acc[nt] = __builtin_amdgcn_mfma_f32_16x16x32_f16(a, bb, acc[nt], 0, 0, 0);
        }
    }
    for (int r = 0; r < 4; r++) {
        int c = c0 + wv * 16 + quad * 4 + r;
        float bias = load1f(bW, c, isf32);
        for (int nt = 0; nt < 8; nt++) {
            int n = n0 + nt * 16 + l16;
            size_t idx = (size_t)(b * C_ + c) * N_ + n;
            float zv = acc[nt][r] + bias + load1f(x, idx, isf32);
            if (isf32) ((float*)z)[idx] = zv;
            else       ((unsigned short*)z)[idx] = f2bf(zv);
        }
    }
}

// ---------------------------------------------------------------------------
extern "C" void kernel_launch(void* const* d_in, const int* in_sizes, int n_in,
                              void* d_out, int out_size, void* d_ws, size_t ws_size,
                              hipStream_t stream) {
    const void* x  = d_in[0];
    const void* wt = d_in[1];
    const void* bt = d_in[2];
    const void* wp = d_in[3];
    const void* bp = d_in[4];
    const void* wg = d_in[5];
    const void* bg = d_in[6];
    const void* wW = d_in[7];
    const void* bW = d_in[8];

    // split factor from ws_size (constant across calls -> graph-safe)
    const size_t base = 64 + 8388608 /*thph*/ + 4194304 /*gT*/;
    const size_t per_split = 4194304 /*partO*/ + 131072 /*pm+pl*/;
    int S = 6;   // 768 blocks -> 3 blocks/CU (LDS-fit)
    while (S > 1 && base + (size_t)S * per_split > ws_size) S--;

    char* p = (char*)d_ws;
    int* flag = (int*)p;                    p += 64;
    unsigned short* thph = (unsigned short*)p;  p += 8388608;
    unsigned short* gT   = (unsigned short*)p;  p += 4194304;
    unsigned short* partO = (unsigned short*)p; p += (size_t)S * 4194304;
    float* pm = (float*)p;                  p += (size_t)S * 65536;
    float* pl = (float*)p;
    unsigned short* y = gT;   // gT dead after attn_partial; reuse for y

    detect_kernel<<<1, 256, 0, stream>>>((const unsigned short*)x, flag);

    dim3 g1(N_ / 64, B_);
    qkv_kernel<<<g1, 512, 0, stream>>>(x, wt, wp, wg, bt, bp, bg, flag, thph, gT);

    dim3 g2(N_ / 128, S, B_);
    attn_partial<<<g2, 512, 0, stream>>>(thph, gT, partO, pm, pl, S);

    merge_kernel<<<(B_ * N_ * 32) / 256, 256, 0, stream>>>(partO, pm, pl, y, S);

    dim3 g3(N_ / 128, C_ / 64, B_);
    out_kernel<<<g3, 256, 0, stream>>>(y, wW, bW, x, flag, d_out);
}

// Round 10
// 221.604 us; speedup vs baseline: 1.0736x; 1.0736x over previous
//
#include <hip/hip_runtime.h>

#define B_    4
#define C_    256
#define O_    128
#define N_    4096
#define THW   256     // thph row width (theta | phi)
#define TILES 64      // N/64 key tiles (attn uses TK=64)

typedef __attribute__((ext_vector_type(8))) _Float16 f16x8;
typedef __attribute__((ext_vector_type(4))) float    f32x4;

struct __align__(8) us4 { unsigned short x, y, z, w; };

__device__ __forceinline__ float bf2f(unsigned short u) {
    unsigned v = ((unsigned)u) << 16;
    union { unsigned u; float f; } c; c.u = v; return c.f;
}
__device__ __forceinline__ unsigned short f2bf(float f) {
    union { float f; unsigned u; } c; c.f = f;
    unsigned r = c.u + 0x7fffu + ((c.u >> 16) & 1u);
    return (unsigned short)(r >> 16);
}
__device__ __forceinline__ unsigned short f2h(float f) {
    _Float16 h = (_Float16)f;
    union { _Float16 h; unsigned short s; } c; c.h = h; return c.s;
}
__device__ __forceinline__ float h2f(unsigned short s) {
    union { unsigned short s; _Float16 h; } c; c.s = s; return (float)c.h;
}

__device__ __forceinline__ void load4f(const void* base, size_t idx, int isf32, float o[4]) {
    if (isf32) {
        float4 v = *(const float4*)((const float*)base + idx);
        o[0] = v.x; o[1] = v.y; o[2] = v.z; o[3] = v.w;
    } else {
        us4 v = *(const us4*)((const unsigned short*)base + idx);
        o[0] = bf2f(v.x); o[1] = bf2f(v.y); o[2] = bf2f(v.z); o[3] = bf2f(v.w);
    }
}
__device__ __forceinline__ float load1f(const void* base, size_t idx, int isf32) {
    return isf32 ? ((const float*)base)[idx] : bf2f(((const unsigned short*)base)[idx]);
}

// ---------------------------------------------------------------------------
// Kernel 0: input dtype detector (fp32 confirmed live; kept for robustness).
// ---------------------------------------------------------------------------
__global__ __launch_bounds__(256) void detect_kernel(
    const unsigned short* __restrict__ xu, int* __restrict__ flag)
{
    __shared__ int cnt;
    if (threadIdx.x == 0) cnt = 0;
    __syncthreads();
    int local = 0;
    for (int i = threadIdx.x; i < 4096; i += 256) {
        unsigned short u = xu[2 * i];
        int e = (u >> 7) & 0xFF;
        if (e == 0xFF || e >= 0x90 || (e > 0 && e <= 0x60)) local++;
    }
    atomicAdd(&cnt, local);
    __syncthreads();
    if (threadIdx.x == 0) *flag = (cnt > 1024) ? 1 : 0;
}

// ---------------------------------------------------------------------------
// Kernel 1: fused conv1x1 x3, one block per 64-n tile. grid (N/64, B),
// 512 threads = 8 waves = 4 wv_n (16-row n-subtiles) x 2 wv_jg (192-j groups).
// NOTE __launch_bounds__(512, 1): 2nd arg is min BLOCKS/CU (CUDA semantics,
// measured r9: (512,2)->cap 128 + 105MB scratch spill; (512,4) attn->64).
// Cap 256 here -> areg 32 + acc 48 + wreg 24 + addr fits, no spill.
// - x loaded ONCE into registers (areg, per-wave n-subtile, full C).
// - Weights double-buffered in LDS by 32-c chunks, 2-deep reg prefetch,
//   ONE barrier per chunk; Bs[384][40] layout is bank-uniform.
// - j<256 -> thph; j>=256 -> g transposed via LDS -> gT coalesced.
// ---------------------------------------------------------------------------
__global__ __launch_bounds__(512, 1) void qkv_kernel(
    const void* __restrict__ x,    // [B][C][N] fp32 or bf16
    const void* __restrict__ wt, const void* __restrict__ wp,
    const void* __restrict__ wg,
    const void* __restrict__ bt, const void* __restrict__ bp,
    const void* __restrict__ bg,
    const int*  __restrict__ flag,
    unsigned short* __restrict__ thph,  // fp16 [B][N][256]
    unsigned short* __restrict__ gT)    // fp16 [B][128][N]
{
    const int isf32 = *flag;
    const int b  = blockIdx.y;
    const int n0 = blockIdx.x * 64;
    const int tid  = threadIdx.x;
    const int wv   = tid >> 6, lane = tid & 63;
    const int quad = lane >> 4, l16 = lane & 15;
    const int wv_n  = wv & 3;       // n-subtile [0,4)
    const int wv_jg = wv >> 2;      // j-group [0,2), 192 j each

    __shared__ alignas(16) unsigned short smem[2 * 384 * 40];  // 61440 B
    unsigned short (*Bs)[384 * 40] = (unsigned short(*)[384 * 40])smem;
    unsigned short (*T)[68] = (unsigned short(*)[68])smem;     // [128][68]

    // ---- upfront A fragments: areg[chunk] = A[n=own 16-row subtile][k=32c]
    f16x8 areg[8];
    {
        int n = n0 + wv_n * 16 + l16;
        size_t xb = (size_t)b * C_ * N_ + n;
        #pragma unroll
        for (int s8 = 0; s8 < 8; s8++) {
            f16x8 fr;
            #pragma unroll
            for (int e = 0; e < 8; e++) {
                int c = s8 * 32 + quad * 8 + e;
                fr[e] = (_Float16)load1f(x, xb + (size_t)c * N_, isf32);
            }
            areg[s8] = fr;
        }
    }

    // ---- weight chunk load/stage (double-buffer + 2-deep reg prefetch) ----
    us4 wreg[2][6];
    auto loadW = [&](int s8, int slot) {
        #pragma unroll
        for (int it = 0; it < 6; it++) {
            int idx = it * 512 + tid;           // [0,3072) us4 units
            int j = idx >> 3, cg = idx & 7;     // j in [0,384), c = s8*32+cg*4
            const void* wsel = j < 128 ? wt : (j < 256 ? wp : wg);
            float v[4];
            load4f(wsel, (size_t)(j & 127) * C_ + s8 * 32 + cg * 4, isf32, v);
            us4 h;
            h.x = f2h(v[0]); h.y = f2h(v[1]); h.z = f2h(v[2]); h.w = f2h(v[3]);
            wreg[slot][it] = h;
        }
    };
    auto stageW = [&](int buf, int slot) {
        #pragma unroll
        for (int it = 0; it < 6; it++) {
            int idx = it * 512 + tid;
            int j = idx >> 3, cg = idx & 7;
            *(us4*)&Bs[buf][j * 40 + cg * 4] = wreg[slot][it];
        }
    };

    loadW(0, 0);
    loadW(1, 1);
    stageW(0, 0);

    f32x4 acc[12];
    #pragma unroll
    for (int jt = 0; jt < 12; jt++) acc[jt] = (f32x4)0.f;

    for (int i = 0; i < 8; i++) {
        __syncthreads();   // chunk i staged; own prior-buffer reads done pre-barrier
        int buf = i & 1;
        #pragma unroll
        for (int jt = 0; jt < 12; jt++) {
            f16x8 bfrag = *(const f16x8*)&Bs[buf][(wv_jg * 192 + jt * 16 + l16) * 40 + quad * 8];
            acc[jt] = __builtin_amdgcn_mfma_f32_16x16x32_f16(areg[i], bfrag, acc[jt], 0, 0, 0);
        }
        if (i + 1 < 8) {
            stageW((i + 1) & 1, (i + 1) & 1);
            if (i + 2 < 8) loadW(i + 2, i & 1);
        }
    }

    // ---- epilogue: D col=j(l16), row=n(quad*4+r) ----
    #pragma unroll
    for (int jt = 0; jt < 12; jt++) {
        int j = wv_jg * 192 + jt * 16 + l16;
        if (j < 256) {   // uniform per (wv_jg, jt)
            const void* bsel = j < 128 ? bt : bp;
            float bias = load1f(bsel, j & 127, isf32);
            #pragma unroll
            for (int r = 0; r < 4; r++) {
                int n = n0 + wv_n * 16 + quad * 4 + r;
                thph[(size_t)(b * N_ + n) * THW + j] = f2h(acc[jt][r] + bias);
            }
        }
    }
    __syncthreads();   // all Bs reads done before overwrite by T
    #pragma unroll
    for (int jt = 0; jt < 12; jt++) {
        int j = wv_jg * 192 + jt * 16 + l16;
        if (j >= 256) {
            float bias = load1f(bg, j - 256, isf32);
            #pragma unroll
            for (int r = 0; r < 4; r++) {
                int nl = wv_n * 16 + quad * 4 + r;
                T[j - 256][nl] = f2h(acc[jt][r] + bias);
            }
        }
    }
    __syncthreads();
    #pragma unroll
    for (int it = 0; it < 4; it++) {
        int idx = it * 512 + tid;   // [0,2048) us4
        int j = idx >> 4, ng = idx & 15;
        *(us4*)(gT + ((size_t)(b * O_ + j)) * N_ + n0 + ng * 4) = *(const us4*)&T[j][ng * 4];
    }
}

// ---------------------------------------------------------------------------
// Kernel 2: flash-attention partial (proven r7 structure; S=6 -> 768 blocks
// = 3 blocks/CU, LDS 3x54272 = 162816 <= 163840).
// ---------------------------------------------------------------------------
__global__ __launch_bounds__(512, 4) void attn_partial(
    const unsigned short* __restrict__ thph,  // fp16 [B][N][256]
    const unsigned short* __restrict__ gT,    // fp16 [B][128][N]
    unsigned short* __restrict__ partO,       // fp16 [S][B][N][128]
    float* __restrict__ pm,                   // [S][B][N]
    float* __restrict__ pl,                   // [S][B][N]
    int S)
{
    const int b    = blockIdx.z;
    const int s_id = blockIdx.y;
    const int n0   = blockIdx.x * 128;
    const int tid  = threadIdx.x;
    const int wv   = tid >> 6, lane = tid & 63;
    const int quad = lane >> 4, l16 = lane & 15;

    const int t0 = (TILES * s_id) / S;
    const int t1 = (TILES * (s_id + 1)) / S;

    __shared__ alignas(16) unsigned short Ks[64][136];
    __shared__ alignas(16) unsigned short Gs[128][72];
    __shared__ alignas(16) unsigned short Ps[8][16][72];

    f16x8 qf[4];
    {
        int qrow = n0 + wv * 16 + l16;
        const unsigned short* qp = thph + (size_t)(b * N_ + qrow) * THW;
        for (int s = 0; s < 4; s++)
            qf[s] = *(const f16x8*)(qp + s * 32 + quad * 8);
    }

    f32x4 oacc[8];
    for (int i = 0; i < 8; i++) oacc[i] = (f32x4)0.f;
    float mstate = -INFINITY, lstate = 0.f;

    us4 kreg[4], greg[4];
    auto prefetch = [&](int mt) {
        int m0 = mt * 64;
        #pragma unroll
        for (int it = 0; it < 4; it++) {
            int l = it * 512 + tid;
            int mm = l >> 5, og = l & 31;
            kreg[it] = *(const us4*)(thph + (size_t)(b * N_ + m0 + mm) * THW + O_ + og * 4);
        }
        #pragma unroll
        for (int it = 0; it < 4; it++) {
            int l = it * 512 + tid;
            int o = l >> 4, ng = l & 15;
            greg[it] = *(const us4*)(gT + ((size_t)(b * O_ + o)) * N_ + m0 + ng * 4);
        }
    };
    prefetch(t0);

    for (int mt = t0; mt < t1; mt++) {
        __syncthreads();
        #pragma unroll
        for (int it = 0; it < 4; it++) {
            int l = it * 512 + tid;
            int mm = l >> 5, og = l & 31;
            *(us4*)&Ks[mm][og * 4] = kreg[it];
        }
        #pragma unroll
        for (int it = 0; it < 4; it++) {
            int l = it * 512 + tid;
            int o = l >> 4, ng = l & 15;
            *(us4*)&Gs[o][ng * 4] = greg[it];
        }
        __syncthreads();
        if (mt + 1 < t1) prefetch(mt + 1);

        f32x4 sacc[4];
        for (int kt = 0; kt < 4; kt++) sacc[kt] = (f32x4)0.f;
        for (int s = 0; s < 4; s++) {
            for (int kt = 0; kt < 4; kt++) {
                f16x8 kb = *(const f16x8*)&Ks[kt * 16 + l16][s * 32 + quad * 8];
                sacc[kt] = __builtin_amdgcn_mfma_f32_16x16x32_f16(kb, qf[s], sacc[kt], 0, 0, 0);
            }
        }

        float rm = fmaxf(fmaxf(fmaxf(sacc[0][0], sacc[0][1]), fmaxf(sacc[0][2], sacc[0][3])),
                         fmaxf(fmaxf(sacc[1][0], sacc[1][1]), fmaxf(sacc[1][2], sacc[1][3])));
        rm = fmaxf(rm, fmaxf(fmaxf(fmaxf(sacc[2][0], sacc[2][1]), fmaxf(sacc[2][2], sacc[2][3])),
                             fmaxf(fmaxf(sacc[3][0], sacc[3][1]), fmaxf(sacc[3][2], sacc[3][3]))));
        rm = fmaxf(rm, __shfl_xor(rm, 16));
        rm = fmaxf(rm, __shfl_xor(rm, 32));

        float mnew  = fmaxf(mstate, rm);
        float alpha = __expf(mstate - mnew);
        mstate = mnew;

        float rs = 0.f;
        #pragma unroll
        for (int kt = 0; kt < 4; kt++) {
            float p0 = __expf(sacc[kt][0] - mnew);
            float p1 = __expf(sacc[kt][1] - mnew);
            float p2 = __expf(sacc[kt][2] - mnew);
            float p3 = __expf(sacc[kt][3] - mnew);
            rs += (p0 + p1) + (p2 + p3);
            us4 pk;
            pk.x = f2h(p0); pk.y = f2h(p1); pk.z = f2h(p2); pk.w = f2h(p3);
            *(us4*)&Ps[wv][l16][kt * 16 + quad * 4] = pk;
        }
        rs += __shfl_xor(rs, 16);
        rs += __shfl_xor(rs, 32);
        lstate = lstate * alpha + rs;

        float av[4];
        #pragma unroll
        for (int r = 0; r < 4; r++) av[r] = __shfl(alpha, quad * 4 + r);
        #pragma unroll
        for (int jt = 0; jt < 8; jt++)
            #pragma unroll
            for (int r = 0; r < 4; r++) oacc[jt][r] *= av[r];

        for (int s = 0; s < 2; s++) {
            f16x8 pa = *(const f16x8*)&Ps[wv][l16][s * 32 + quad * 8];
            for (int jt = 0; jt < 8; jt++) {
                f16x8 gb = *(const f16x8*)&Gs[jt * 16 + l16][s * 32 + quad * 8];
                oacc[jt] = __builtin_amdgcn_mfma_f32_16x16x32_f16(pa, gb, oacc[jt], 0, 0, 0);
            }
        }
    }

    for (int r = 0; r < 4; r++) {
        int n = n0 + wv * 16 + quad * 4 + r;
        size_t rowb = ((size_t)(s_id * B_ + b) * N_ + n) * O_;
        for (int jt = 0; jt < 8; jt++)
            partO[rowb + jt * 16 + l16] = f2h(oacc[jt][r]);
    }
    if (quad == 0) {
        int n = n0 + wv * 16 + l16;
        pm[(size_t)(s_id * B_ + b) * N_ + n] = mstate;
        pl[(size_t)(s_id * B_ + b) * N_ + n] = lstate;
    }
}

// ---------------------------------------------------------------------------
// Kernel 2b: merge split-K partials -> y[b][n][o] (normalized fp16).
// ---------------------------------------------------------------------------
__global__ __launch_bounds__(256) void merge_kernel(
    const unsigned short* __restrict__ partO,
    const float* __restrict__ pm, const float* __restrict__ pl,
    unsigned short* __restrict__ y,
    int S)
{
    int idx = blockIdx.x * 256 + threadIdx.x;
    int bn  = idx >> 5;
    int og  = idx & 31;
    const int BN = B_ * N_;

    float M = -INFINITY;
    for (int s = 0; s < S; s++) M = fmaxf(M, pm[(size_t)s * BN + bn]);
    float w[8];
    float L = 0.f;
    for (int s = 0; s < S; s++) {
        w[s] = __expf(pm[(size_t)s * BN + bn] - M);
        L += w[s] * pl[(size_t)s * BN + bn];
    }
    float inv = 1.0f / L;

    float a0 = 0.f, a1 = 0.f, a2 = 0.f, a3 = 0.f;
    for (int s = 0; s < S; s++) {
        us4 v = *(const us4*)(partO + ((size_t)s * BN + bn) * O_ + og * 4);
        a0 += h2f(v.x) * w[s];
        a1 += h2f(v.y) * w[s];
        a2 += h2f(v.z) * w[s];
        a3 += h2f(v.w) * w[s];
    }
    us4 r;
    r.x = f2h(a0 * inv); r.y = f2h(a1 * inv);
    r.z = f2h(a2 * inv); r.w = f2h(a3 * inv);
    *(us4*)(y + (size_t)bn * O_ + og * 4) = r;
}

// ---------------------------------------------------------------------------
// Kernel 3: z[b][c][n] = sum_o wW[c][o] y[b][n][o] + bW[c] + x[b][c][n]
// ---------------------------------------------------------------------------
__global__ __launch_bounds__(256) void out_kernel(
    const unsigned short* __restrict__ y,
    const void* __restrict__ wW,
    const void* __restrict__ bW,
    const void* __restrict__ x,
    const int*  __restrict__ flag,
    void* __restrict__ z)
{
    const int isf32 = *flag;
    const int b  = blockIdx.z;
    const int c0 = blockIdx.y * 64;
    const int n0 = blockIdx.x * 128;
    const int tid  = threadIdx.x;
    const int wv   = tid >> 6, lane = tid & 63;
    const int quad = lane >> 4, l16 = lane & 15;

    __shared__ alignas(16) unsigned short Ys[128][136];
    __shared__ alignas(16) unsigned short Ws[64][136];

    for (int it = 0; it < 16; it++) {
        int l = it * 256 + tid;
        int nn = l >> 5;
        int og = l & 31;
        us4 v = *(const us4*)(y + (size_t)(b * N_ + n0 + nn) * O_ + og * 4);
        *(us4*)&Ys[nn][og * 4] = v;
    }
    for (int it = 0; it < 8; it++) {
        int l = it * 256 + tid;
        int cc = l >> 5;
        int og = l & 31;
        float v[4];
        load4f(wW, (size_t)(c0 + cc) * O_ + og * 4, isf32, v);
        Ws[cc][og * 4 + 0] = f2h(v[0]);
        Ws[cc][og * 4 + 1] = f2h(v[1]);
        Ws[cc][og * 4 + 2] = f2h(v[2]);
        Ws[cc][og * 4 + 3] = f2h(v[3]);
    }
    __syncthreads();

    f32x4 acc[8];
    for (int i = 0; i < 8; i++) acc[i] = (f32x4)0.f;
    for (int s = 0; s < 4; s++) {
        f16x8 a = *(const f16x8*)&Ws[wv * 16 + l16][s * 32 + quad * 8];
        for (int nt = 0; nt < 8; nt++) {
            f16x8 bb = *(const f16x8*)&Ys[nt * 16 + l16][s * 32 + quad * 8];
            acc[nt] = __builtin_amdgcn_mfma_f32_16x16x32_f16(a, bb, acc[nt], 0, 0, 0);
        }
    }
    for (int r = 0; r < 4; r++) {
        int c = c0 + wv * 16 + quad * 4 + r;
        float bias = load1f(bW, c, isf32);
        for (int nt = 0; nt < 8; nt++) {
            int n = n0 + nt * 16 + l16;
            size_t idx = (size_t)(b * C_ + c) * N_ + n;
            float zv = acc[nt][r] + bias + load1f(x, idx, isf32);
            if (isf32) ((float*)z)[idx] = zv;
            else       ((unsigned short*)z)[idx] = f2bf(zv);
        }
    }
}

// ---------------------------------------------------------------------------
extern "C" void kernel_launch(void* const* d_in, const int* in_sizes, int n_in,
                              void* d_out, int out_size, void* d_ws, size_t ws_size,
                              hipStream_t stream) {
    const void* x  = d_in[0];
    const void* wt = d_in[1];
    const void* bt = d_in[2];
    const void* wp = d_in[3];
    const void* bp = d_in[4];
    const void* wg = d_in[5];
    const void* bg = d_in[6];
    const void* wW = d_in[7];
    const void* bW = d_in[8];

    // split factor from ws_size (constant across calls -> graph-safe)
    const size_t base = 64 + 8388608 /*thph*/ + 4194304 /*gT*/;
    const size_t per_split = 4194304 /*partO*/ + 131072 /*pm+pl*/;
    int S = 6;   // 768 blocks -> 3 blocks/CU (LDS-fit)
    while (S > 1 && base + (size_t)S * per_split > ws_size) S--;

    char* p = (char*)d_ws;
    int* flag = (int*)p;                    p += 64;
    unsigned short* thph = (unsigned short*)p;  p += 8388608;
    unsigned short* gT   = (unsigned short*)p;  p += 4194304;
    unsigned short* partO = (unsigned short*)p; p += (size_t)S * 4194304;
    float* pm = (float*)p;                  p += (size_t)S * 65536;
    float* pl = (float*)p;
    unsigned short* y = gT;   // gT dead after attn_partial; reuse for y

    detect_kernel<<<1, 256, 0, stream>>>((const unsigned short*)x, flag);

    dim3 g1(N_ / 64, B_);
    qkv_kernel<<<g1, 512, 0, stream>>>(x, wt, wp, wg, bt, bp, bg, flag, thph, gT);

    dim3 g2(N_ / 128, S, B_);
    attn_partial<<<g2, 512, 0, stream>>>(thph, gT, partO, pm, pl, S);

    merge_kernel<<<(B_ * N_ * 32) / 256, 256, 0, stream>>>(partO, pm, pl, y, S);

    dim3 g3(N_ / 128, C_ / 64, B_);
    out_kernel<<<g3, 256, 0, stream>>>(y, wW, bW, x, flag, d_out);
}

// Round 11
// 216.092 us; speedup vs baseline: 1.1010x; 1.0255x over previous
//
#include <hip/hip_runtime.h>

#define B_    4
#define C_    256
#define O_    128
#define N_    4096
#define THW   256     // thph row width (theta | phi)
#define TILES 64      // N/64 key tiles (attn uses TK=64)

typedef __attribute__((ext_vector_type(8))) _Float16 f16x8;
typedef __attribute__((ext_vector_type(4))) float    f32x4;

struct __align__(8) us4 { unsigned short x, y, z, w; };

__device__ __forceinline__ float bf2f(unsigned short u) {
    unsigned v = ((unsigned)u) << 16;
    union { unsigned u; float f; } c; c.u = v; return c.f;
}
__device__ __forceinline__ unsigned short f2bf(float f) {
    union { float f; unsigned u; } c; c.f = f;
    unsigned r = c.u + 0x7fffu + ((c.u >> 16) & 1u);
    return (unsigned short)(r >> 16);
}
__device__ __forceinline__ unsigned short f2h(float f) {
    _Float16 h = (_Float16)f;
    union { _Float16 h; unsigned short s; } c; c.h = h; return c.s;
}
__device__ __forceinline__ float h2f(unsigned short s) {
    union { unsigned short s; _Float16 h; } c; c.s = s; return (float)c.h;
}

__device__ __forceinline__ void load4f(const void* base, size_t idx, int isf32, float o[4]) {
    if (isf32) {
        float4 v = *(const float4*)((const float*)base + idx);
        o[0] = v.x; o[1] = v.y; o[2] = v.z; o[3] = v.w;
    } else {
        us4 v = *(const us4*)((const unsigned short*)base + idx);
        o[0] = bf2f(v.x); o[1] = bf2f(v.y); o[2] = bf2f(v.z); o[3] = bf2f(v.w);
    }
}
__device__ __forceinline__ float load1f(const void* base, size_t idx, int isf32) {
    return isf32 ? ((const float*)base)[idx] : bf2f(((const unsigned short*)base)[idx]);
}

// ---------------------------------------------------------------------------
// Kernel 0: input dtype detector (fp32 confirmed live; kept for robustness).
// ---------------------------------------------------------------------------
__global__ __launch_bounds__(256) void detect_kernel(
    const unsigned short* __restrict__ xu, int* __restrict__ flag)
{
    __shared__ int cnt;
    if (threadIdx.x == 0) cnt = 0;
    __syncthreads();
    int local = 0;
    for (int i = threadIdx.x; i < 4096; i += 256) {
        unsigned short u = xu[2 * i];
        int e = (u >> 7) & 0xFF;
        if (e == 0xFF || e >= 0x90 || (e > 0 && e <= 0x60)) local++;
    }
    atomicAdd(&cnt, local);
    __syncthreads();
    if (threadIdx.x == 0) *flag = (cnt > 1024) ? 1 : 0;
}

// ---------------------------------------------------------------------------
// Kernel 1: fused conv1x1 x3, one block per 64-n tile. grid (N/64, B),
// 512 threads = 8 waves = 4 wv_n (16-row n-subtiles) x 2 wv_jg (192-j groups).
// __launch_bounds__(512, 1): 2nd arg = min BLOCKS/CU (measured r9:
// (512,2)->cap 128 VGPR + spill). Main K-loop MUST be fully unrolled:
// r10 measured VGPR=68 + 49MB scratch because dynamically-indexed areg[i]
// was scratch-allocated; #pragma unroll makes all indices static.
// ---------------------------------------------------------------------------
__global__ __launch_bounds__(512, 1) void qkv_kernel(
    const void* __restrict__ x,    // [B][C][N] fp32 or bf16
    const void* __restrict__ wt, const void* __restrict__ wp,
    const void* __restrict__ wg,
    const void* __restrict__ bt, const void* __restrict__ bp,
    const void* __restrict__ bg,
    const int*  __restrict__ flag,
    unsigned short* __restrict__ thph,  // fp16 [B][N][256]
    unsigned short* __restrict__ gT)    // fp16 [B][128][N]
{
    const int isf32 = *flag;
    const int b  = blockIdx.y;
    const int n0 = blockIdx.x * 64;
    const int tid  = threadIdx.x;
    const int wv   = tid >> 6, lane = tid & 63;
    const int quad = lane >> 4, l16 = lane & 15;
    const int wv_n  = wv & 3;       // n-subtile [0,4)
    const int wv_jg = wv >> 2;      // j-group [0,2), 192 j each

    __shared__ alignas(16) unsigned short smem[2 * 384 * 40];  // 61440 B
    unsigned short (*Bs)[384 * 40] = (unsigned short(*)[384 * 40])smem;
    unsigned short (*T)[68] = (unsigned short(*)[68])smem;     // [128][68]

    // ---- upfront A fragments: areg[chunk] = A[n=own 16-row subtile][k=32c]
    f16x8 areg[8];
    {
        int n = n0 + wv_n * 16 + l16;
        size_t xb = (size_t)b * C_ * N_ + n;
        #pragma unroll
        for (int s8 = 0; s8 < 8; s8++) {
            f16x8 fr;
            #pragma unroll
            for (int e = 0; e < 8; e++) {
                int c = s8 * 32 + quad * 8 + e;
                fr[e] = (_Float16)load1f(x, xb + (size_t)c * N_, isf32);
            }
            areg[s8] = fr;
        }
    }

    // ---- weight chunk load/stage (double-buffer + 2-deep reg prefetch) ----
    us4 wreg[2][6];
    auto loadW = [&](int s8, int slot) {
        #pragma unroll
        for (int it = 0; it < 6; it++) {
            int idx = it * 512 + tid;           // [0,3072) us4 units
            int j = idx >> 3, cg = idx & 7;     // j in [0,384), c = s8*32+cg*4
            const void* wsel = j < 128 ? wt : (j < 256 ? wp : wg);
            float v[4];
            load4f(wsel, (size_t)(j & 127) * C_ + s8 * 32 + cg * 4, isf32, v);
            us4 h;
            h.x = f2h(v[0]); h.y = f2h(v[1]); h.z = f2h(v[2]); h.w = f2h(v[3]);
            wreg[slot][it] = h;
        }
    };
    auto stageW = [&](int buf, int slot) {
        #pragma unroll
        for (int it = 0; it < 6; it++) {
            int idx = it * 512 + tid;
            int j = idx >> 3, cg = idx & 7;
            *(us4*)&Bs[buf][j * 40 + cg * 4] = wreg[slot][it];
        }
    };

    loadW(0, 0);
    loadW(1, 1);
    stageW(0, 0);

    f32x4 acc[12];
    #pragma unroll
    for (int jt = 0; jt < 12; jt++) acc[jt] = (f32x4)0.f;

    #pragma unroll   // CRITICAL: keeps areg/wreg statically indexed (r10 spill fix)
    for (int i = 0; i < 8; i++) {
        __syncthreads();   // chunk i staged; own prior-buffer reads done pre-barrier
        int buf = i & 1;
        #pragma unroll
        for (int jt = 0; jt < 12; jt++) {
            f16x8 bfrag = *(const f16x8*)&Bs[buf][(wv_jg * 192 + jt * 16 + l16) * 40 + quad * 8];
            acc[jt] = __builtin_amdgcn_mfma_f32_16x16x32_f16(areg[i], bfrag, acc[jt], 0, 0, 0);
        }
        if (i + 1 < 8) {
            stageW((i + 1) & 1, (i + 1) & 1);
            if (i + 2 < 8) loadW(i + 2, i & 1);
        }
    }

    // ---- epilogue: D col=j(l16), row=n(quad*4+r) ----
    #pragma unroll
    for (int jt = 0; jt < 12; jt++) {
        int j = wv_jg * 192 + jt * 16 + l16;
        if (j < 256) {   // uniform per (wv_jg, jt)
            const void* bsel = j < 128 ? bt : bp;
            float bias = load1f(bsel, j & 127, isf32);
            #pragma unroll
            for (int r = 0; r < 4; r++) {
                int n = n0 + wv_n * 16 + quad * 4 + r;
                thph[(size_t)(b * N_ + n) * THW + j] = f2h(acc[jt][r] + bias);
            }
        }
    }
    __syncthreads();   // all Bs reads done before overwrite by T
    #pragma unroll
    for (int jt = 0; jt < 12; jt++) {
        int j = wv_jg * 192 + jt * 16 + l16;
        if (j >= 256) {
            float bias = load1f(bg, j - 256, isf32);
            #pragma unroll
            for (int r = 0; r < 4; r++) {
                int nl = wv_n * 16 + quad * 4 + r;
                T[j - 256][nl] = f2h(acc[jt][r] + bias);
            }
        }
    }
    __syncthreads();
    #pragma unroll
    for (int it = 0; it < 4; it++) {
        int idx = it * 512 + tid;   // [0,2048) us4
        int j = idx >> 4, ng = idx & 15;
        *(us4*)(gT + ((size_t)(b * O_ + j)) * N_ + n0 + ng * 4) = *(const us4*)&T[j][ng * 4];
    }
}

// ---------------------------------------------------------------------------
// Kernel 2: flash-attention partial (r7-proven structure; S=4 -> 512 blocks
// = 2 blocks/CU. r10 measured: S=6 does NOT fit 3/CU and regresses — keep 4.)
// ---------------------------------------------------------------------------
__global__ __launch_bounds__(512, 4) void attn_partial(
    const unsigned short* __restrict__ thph,  // fp16 [B][N][256]
    const unsigned short* __restrict__ gT,    // fp16 [B][128][N]
    unsigned short* __restrict__ partO,       // fp16 [S][B][N][128]
    float* __restrict__ pm,                   // [S][B][N]
    float* __restrict__ pl,                   // [S][B][N]
    int S)
{
    const int b    = blockIdx.z;
    const int s_id = blockIdx.y;
    const int n0   = blockIdx.x * 128;
    const int tid  = threadIdx.x;
    const int wv   = tid >> 6, lane = tid & 63;
    const int quad = lane >> 4, l16 = lane & 15;

    const int t0 = (TILES * s_id) / S;
    const int t1 = (TILES * (s_id + 1)) / S;

    __shared__ alignas(16) unsigned short Ks[64][136];
    __shared__ alignas(16) unsigned short Gs[128][72];
    __shared__ alignas(16) unsigned short Ps[8][16][72];

    f16x8 qf[4];
    {
        int qrow = n0 + wv * 16 + l16;
        const unsigned short* qp = thph + (size_t)(b * N_ + qrow) * THW;
        for (int s = 0; s < 4; s++)
            qf[s] = *(const f16x8*)(qp + s * 32 + quad * 8);
    }

    f32x4 oacc[8];
    for (int i = 0; i < 8; i++) oacc[i] = (f32x4)0.f;
    float mstate = -INFINITY, lstate = 0.f;

    us4 kreg[4], greg[4];
    auto prefetch = [&](int mt) {
        int m0 = mt * 64;
        #pragma unroll
        for (int it = 0; it < 4; it++) {
            int l = it * 512 + tid;
            int mm = l >> 5, og = l & 31;
            kreg[it] = *(const us4*)(thph + (size_t)(b * N_ + m0 + mm) * THW + O_ + og * 4);
        }
        #pragma unroll
        for (int it = 0; it < 4; it++) {
            int l = it * 512 + tid;
            int o = l >> 4, ng = l & 15;
            greg[it] = *(const us4*)(gT + ((size_t)(b * O_ + o)) * N_ + m0 + ng * 4);
        }
    };
    prefetch(t0);

    for (int mt = t0; mt < t1; mt++) {
        __syncthreads();
        #pragma unroll
        for (int it = 0; it < 4; it++) {
            int l = it * 512 + tid;
            int mm = l >> 5, og = l & 31;
            *(us4*)&Ks[mm][og * 4] = kreg[it];
        }
        #pragma unroll
        for (int it = 0; it < 4; it++) {
            int l = it * 512 + tid;
            int o = l >> 4, ng = l & 15;
            *(us4*)&Gs[o][ng * 4] = greg[it];
        }
        __syncthreads();
        if (mt + 1 < t1) prefetch(mt + 1);

        f32x4 sacc[4];
        for (int kt = 0; kt < 4; kt++) sacc[kt] = (f32x4)0.f;
        for (int s = 0; s < 4; s++) {
            for (int kt = 0; kt < 4; kt++) {
                f16x8 kb = *(const f16x8*)&Ks[kt * 16 + l16][s * 32 + quad * 8];
                sacc[kt] = __builtin_amdgcn_mfma_f32_16x16x32_f16(kb, qf[s], sacc[kt], 0, 0, 0);
            }
        }

        float rm = fmaxf(fmaxf(fmaxf(sacc[0][0], sacc[0][1]), fmaxf(sacc[0][2], sacc[0][3])),
                         fmaxf(fmaxf(sacc[1][0], sacc[1][1]), fmaxf(sacc[1][2], sacc[1][3])));
        rm = fmaxf(rm, fmaxf(fmaxf(fmaxf(sacc[2][0], sacc[2][1]), fmaxf(sacc[2][2], sacc[2][3])),
                             fmaxf(fmaxf(sacc[3][0], sacc[3][1]), fmaxf(sacc[3][2], sacc[3][3]))));
        rm = fmaxf(rm, __shfl_xor(rm, 16));
        rm = fmaxf(rm, __shfl_xor(rm, 32));

        float mnew  = fmaxf(mstate, rm);
        float alpha = __expf(mstate - mnew);
        mstate = mnew;

        float rs = 0.f;
        #pragma unroll
        for (int kt = 0; kt < 4; kt++) {
            float p0 = __expf(sacc[kt][0] - mnew);
            float p1 = __expf(sacc[kt][1] - mnew);
            float p2 = __expf(sacc[kt][2] - mnew);
            float p3 = __expf(sacc[kt][3] - mnew);
            rs += (p0 + p1) + (p2 + p3);
            us4 pk;
            pk.x = f2h(p0); pk.y = f2h(p1); pk.z = f2h(p2); pk.w = f2h(p3);
            *(us4*)&Ps[wv][l16][kt * 16 + quad * 4] = pk;
        }
        rs += __shfl_xor(rs, 16);
        rs += __shfl_xor(rs, 32);
        lstate = lstate * alpha + rs;

        float av[4];
        #pragma unroll
        for (int r = 0; r < 4; r++) av[r] = __shfl(alpha, quad * 4 + r);
        #pragma unroll
        for (int jt = 0; jt < 8; jt++)
            #pragma unroll
            for (int r = 0; r < 4; r++) oacc[jt][r] *= av[r];

        for (int s = 0; s < 2; s++) {
            f16x8 pa = *(const f16x8*)&Ps[wv][l16][s * 32 + quad * 8];
            for (int jt = 0; jt < 8; jt++) {
                f16x8 gb = *(const f16x8*)&Gs[jt * 16 + l16][s * 32 + quad * 8];
                oacc[jt] = __builtin_amdgcn_mfma_f32_16x16x32_f16(pa, gb, oacc[jt], 0, 0, 0);
            }
        }
    }

    for (int r = 0; r < 4; r++) {
        int n = n0 + wv * 16 + quad * 4 + r;
        size_t rowb = ((size_t)(s_id * B_ + b) * N_ + n) * O_;
        for (int jt = 0; jt < 8; jt++)
            partO[rowb + jt * 16 + l16] = f2h(oacc[jt][r]);
    }
    if (quad == 0) {
        int n = n0 + wv * 16 + l16;
        pm[(size_t)(s_id * B_ + b) * N_ + n] = mstate;
        pl[(size_t)(s_id * B_ + b) * N_ + n] = lstate;
    }
}

// ---------------------------------------------------------------------------
// Kernel 2b: merge split-K partials -> y[b][n][o] (normalized fp16).
// ---------------------------------------------------------------------------
__global__ __launch_bounds__(256) void merge_kernel(
    const unsigned short* __restrict__ partO,
    const float* __restrict__ pm, const float* __restrict__ pl,
    unsigned short* __restrict__ y,
    int S)
{
    int idx = blockIdx.x * 256 + threadIdx.x;
    int bn  = idx >> 5;
    int og  = idx & 31;
    const int BN = B_ * N_;

    float M = -INFINITY;
    for (int s = 0; s < S; s++) M = fmaxf(M, pm[(size_t)s * BN + bn]);
    float w[8];
    float L = 0.f;
    for (int s = 0; s < S; s++) {
        w[s] = __expf(pm[(size_t)s * BN + bn] - M);
        L += w[s] * pl[(size_t)s * BN + bn];
    }
    float inv = 1.0f / L;

    float a0 = 0.f, a1 = 0.f, a2 = 0.f, a3 = 0.f;
    for (int s = 0; s < S; s++) {
        us4 v = *(const us4*)(partO + ((size_t)s * BN + bn) * O_ + og * 4);
        a0 += h2f(v.x) * w[s];
        a1 += h2f(v.y) * w[s];
        a2 += h2f(v.z) * w[s];
        a3 += h2f(v.w) * w[s];
    }
    us4 r;
    r.x = f2h(a0 * inv); r.y = f2h(a1 * inv);
    r.z = f2h(a2 * inv); r.w = f2h(a3 * inv);
    *(us4*)(y + (size_t)bn * O_ + og * 4) = r;
}

// ---------------------------------------------------------------------------
// Kernel 3: z[b][c][n] = sum_o wW[c][o] y[b][n][o] + bW[c] + x[b][c][n]
// ---------------------------------------------------------------------------
__global__ __launch_bounds__(256) void out_kernel(
    const unsigned short* __restrict__ y,
    const void* __restrict__ wW,
    const void* __restrict__ bW,
    const void* __restrict__ x,
    const int*  __restrict__ flag,
    void* __restrict__ z)
{
    const int isf32 = *flag;
    const int b  = blockIdx.z;
    const int c0 = blockIdx.y * 64;
    const int n0 = blockIdx.x * 128;
    const int tid  = threadIdx.x;
    const int wv   = tid >> 6, lane = tid & 63;
    const int quad = lane >> 4, l16 = lane & 15;

    __shared__ alignas(16) unsigned short Ys[128][136];
    __shared__ alignas(16) unsigned short Ws[64][136];

    for (int it = 0; it < 16; it++) {
        int l = it * 256 + tid;
        int nn = l >> 5;
        int og = l & 31;
        us4 v = *(const us4*)(y + (size_t)(b * N_ + n0 + nn) * O_ + og * 4);
        *(us4*)&Ys[nn][og * 4] = v;
    }
    for (int it = 0; it < 8; it++) {
        int l = it * 256 + tid;
        int cc = l >> 5;
        int og = l & 31;
        float v[4];
        load4f(wW, (size_t)(c0 + cc) * O_ + og * 4, isf32, v);
        Ws[cc][og * 4 + 0] = f2h(v[0]);
        Ws[cc][og * 4 + 1] = f2h(v[1]);
        Ws[cc][og * 4 + 2] = f2h(v[2]);
        Ws[cc][og * 4 + 3] = f2h(v[3]);
    }
    __syncthreads();

    f32x4 acc[8];
    for (int i = 0; i < 8; i++) acc[i] = (f32x4)0.f;
    for (int s = 0; s < 4; s++) {
        f16x8 a = *(const f16x8*)&Ws[wv * 16 + l16][s * 32 + quad * 8];
        for (int nt = 0; nt < 8; nt++) {
            f16x8 bb = *(const f16x8*)&Ys[nt * 16 + l16][s * 32 + quad * 8];
            acc[nt] = __builtin_amdgcn_mfma_f32_16x16x32_f16(a, bb, acc[nt], 0, 0, 0);
        }
    }
    for (int r = 0; r < 4; r++) {
        int c = c0 + wv * 16 + quad * 4 + r;
        float bias = load1f(bW, c, isf32);
        for (int nt = 0; nt < 8; nt++) {
            int n = n0 + nt * 16 + l16;
            size_t idx = (size_t)(b * C_ + c) * N_ + n;
            float zv = acc[nt][r] + bias + load1f(x, idx, isf32);
            if (isf32) ((float*)z)[idx] = zv;
            else       ((unsigned short*)z)[idx] = f2bf(zv);
        }
    }
}

// ---------------------------------------------------------------------------
extern "C" void kernel_launch(void* const* d_in, const int* in_sizes, int n_in,
                              void* d_out, int out_size, void* d_ws, size_t ws_size,
                              hipStream_t stream) {
    const void* x  = d_in[0];
    const void* wt = d_in[1];
    const void* bt = d_in[2];
    const void* wp = d_in[3];
    const void* bp = d_in[4];
    const void* wg = d_in[5];
    const void* bg = d_in[6];
    const void* wW = d_in[7];
    const void* bW = d_in[8];

    // split factor from ws_size (constant across calls -> graph-safe)
    const size_t base = 64 + 8388608 /*thph*/ + 4194304 /*gT*/;
    const size_t per_split = 4194304 /*partO*/ + 131072 /*pm+pl*/;
    int S = 4;   // 512 blocks -> 2 blocks/CU (r10: S=6 regresses)
    while (S > 1 && base + (size_t)S * per_split > ws_size) S--;

    char* p = (char*)d_ws;
    int* flag = (int*)p;                    p += 64;
    unsigned short* thph = (unsigned short*)p;  p += 8388608;
    unsigned short* gT   = (unsigned short*)p;  p += 4194304;
    unsigned short* partO = (unsigned short*)p; p += (size_t)S * 4194304;
    float* pm = (float*)p;                  p += (size_t)S * 65536;
    float* pl = (float*)p;
    unsigned short* y = gT;   // gT dead after attn_partial; reuse for y

    detect_kernel<<<1, 256, 0, stream>>>((const unsigned short*)x, flag);

    dim3 g1(N_ / 64, B_);
    qkv_kernel<<<g1, 512, 0, stream>>>(x, wt, wp, wg, bt, bp, bg, flag, thph, gT);

    dim3 g2(N_ / 128, S, B_);
    attn_partial<<<g2, 512, 0, stream>>>(thph, gT, partO, pm, pl, S);

    merge_kernel<<<(B_ * N_ * 32) / 256, 256, 0, stream>>>(partO, pm, pl, y, S);

    dim3 g3(N_ / 128, C_ / 64, B_);
    out_kernel<<<g3, 256, 0, stream>>>(y, wW, bW, x, flag, d_out);
}